// Round 8
// baseline (441.158 us; speedup 1.0000x reference)
//
#include <hip/hip_runtime.h>
#include <stdint.h>

// Multi_LSTMs: bidirectional 4-head LSTM, BS=8 NT=128 CH=1024 H=512 G=2048.
// R1-R4: poison-poll state exchange, no fences in step loop.
// R5: MFMA split into 2 chains. R6 FAILED fusion. R7 FAILED bundle.
// R8 REFUTED residency. R9 REFUTED spin-traffic.
// R10: LDS_BARRIER (no vmcnt drain) -12us.
// R11 CONFIRMED: loop-top ih prefetch hides under poll wait; rec 266->216us.
// R12 (this round):
//   a) prep pack_x: 4-wide c-block -> 4x 8B stores (was 16x 2B scatter).
//   b) NEW 256x256 BK=64 dbuf GEMM (T3 2-phase recipe + XOR slot swizzle),
//      PARTIAL ROLLOUT on dk=0 only; old m97 kernel keeps dk=1..7. Rec
//      consumes dk=0 from the new kernel -> correctness-verified + isolated
//      dispatch counters before full swap next round.
//   c) rec untouched (R11 form).

typedef __attribute__((ext_vector_type(8))) short short8;
typedef __attribute__((ext_vector_type(4))) float floatx4;
typedef unsigned long long ull;

#define POISON 0x7FC07FC07FC07FC0ull  // 4 x bf16 NaN (stateS)

// Barrier WITHOUT the implicit vmcnt(0) drain: only LDS ops must be visible.
#define LDS_BARRIER()                                       \
  do {                                                      \
    asm volatile("s_waitcnt lgkmcnt(0)" ::: "memory");      \
    __builtin_amdgcn_s_barrier();                           \
  } while (0)

#define GLOAD_LDS16(g, l)                                        \
  __builtin_amdgcn_global_load_lds(                              \
      (const __attribute__((address_space(1))) void*)(g),        \
      (__attribute__((address_space(3))) void*)(l), 16, 0, 0)

__device__ __forceinline__ unsigned short f2bf(float f) {
  unsigned u = __float_as_uint(f);
  u = (u + 0x7fffu + ((u >> 16) & 1u)) >> 16;  // RNE
  return (unsigned short)u;
}
__device__ __forceinline__ float sigm(float x) { return 1.0f / (1.0f + __expf(-x)); }
__device__ __forceinline__ float tanh_f(float x) {
  float ax = fabsf(x);
  float e = __expf(-2.0f * ax);
  float t = (1.0f - e) / (1.0f + e);
  return x < 0.0f ? -t : t;
}

// One prep kernel: pack x (4-wide), cast weights to bf16, poison stateS.
// Work items: pack 262144 | Wih_f 2M | Wih_b 2M | Whh_f 1M | Whh_b 1M | stateS 1M
// boundaries: 262144 / 2359296 / 4456448 / 5505024 / 6553600 / 7602176
__global__ __launch_bounds__(256) void prep_k(
    const float* __restrict__ x,
    const float* __restrict__ Wih_f, const float* __restrict__ Wih_b,
    const float* __restrict__ Whh_f, const float* __restrict__ Whh_b,
    unsigned short* __restrict__ Xp, unsigned short* __restrict__ Wihb,
    unsigned short* __restrict__ Whhb, ull* __restrict__ stateS) {
  size_t i = (size_t)blockIdx.x * 256 + threadIdx.x;
  if (i < 262144) {  // pack x: thread = (m, 4 consecutive c); 8B stores per kh
    int m = (int)i >> 8, cb = (int)i & 255;
    int t = m >> 3, b = m & 7;
    const float* xs = x + ((size_t)((b * 128 + t) * 1024 + cb * 4)) * 4;
    float4 v0 = ((const float4*)xs)[0];
    float4 v1 = ((const float4*)xs)[1];
    float4 v2 = ((const float4*)xs)[2];
    float4 v3 = ((const float4*)xs)[3];
    int o = m * 1024 + cb * 4;  // element offset within a kh-plane
    ushort4 o0 = {f2bf(v0.x), f2bf(v1.x), f2bf(v2.x), f2bf(v3.x)};
    ushort4 o1 = {f2bf(v0.y), f2bf(v1.y), f2bf(v2.y), f2bf(v3.y)};
    ushort4 o2 = {f2bf(v0.z), f2bf(v1.z), f2bf(v2.z), f2bf(v3.z)};
    ushort4 o3 = {f2bf(v0.w), f2bf(v1.w), f2bf(v2.w), f2bf(v3.w)};
    *(ushort4*)(Xp + o)           = o0;
    *(ushort4*)(Xp + 1048576 + o) = o1;
    *(ushort4*)(Xp + 2097152 + o) = o2;
    *(ushort4*)(Xp + 3145728 + o) = o3;
  } else if (i < 2359296) {  // Wih_f: 2M float4
    size_t j = i - 262144;
    float4 v = ((const float4*)Wih_f)[j];
    ushort4 o;
    o.x = f2bf(v.x); o.y = f2bf(v.y); o.z = f2bf(v.z); o.w = f2bf(v.w);
    ((ushort4*)Wihb)[j] = o;
  } else if (i < 4456448) {  // Wih_b
    size_t j = i - 2359296;
    float4 v = ((const float4*)Wih_b)[j];
    ushort4 o;
    o.x = f2bf(v.x); o.y = f2bf(v.y); o.z = f2bf(v.z); o.w = f2bf(v.w);
    ((ushort4*)Wihb)[2097152 + j] = o;
  } else if (i < 5505024) {  // Whh_f: 1M float4
    size_t j = i - 4456448;
    float4 v = ((const float4*)Whh_f)[j];
    ushort4 o;
    o.x = f2bf(v.x); o.y = f2bf(v.y); o.z = f2bf(v.z); o.w = f2bf(v.w);
    ((ushort4*)Whhb)[j] = o;
  } else if (i < 6553600) {  // Whh_b
    size_t j = i - 5505024;
    float4 v = ((const float4*)Whh_b)[j];
    ushort4 o;
    o.x = f2bf(v.x); o.y = f2bf(v.y); o.z = f2bf(v.z); o.w = f2bf(v.w);
    ((ushort4*)Whhb)[1048576 + j] = o;
  } else {  // stateS poison: 1M ull
    stateS[i - 6553600] = POISON;
  }
}

// OLD GEMM (m97 structure), now covering dk = 1..7 only (896 blocks).
// Panel swizzle over 112 panels: bid: xcd=bid&7, q=bid>>3, mt=q&7,
// p=(q>>3)*8+xcd in [0,112), dk=(p>>4)+1, ntl=p&15.
__global__ __launch_bounds__(256) void gemm_ih_k(
    const unsigned short* __restrict__ Xp, const unsigned short* __restrict__ Wb,
    const float* __restrict__ bihf, const float* __restrict__ bhhf,
    const float* __restrict__ bihb, const float* __restrict__ bhhb,
    float* __restrict__ ih) {
  const int bid = blockIdx.x;
  const int xcd = bid & 7;
  const int q   = bid >> 3;            // 0..111
  const int mt  = q & 7;
  const int p   = (q >> 3) * 8 + xcd;  // 0..111
  const int dk  = (p >> 4) + 1;        // 1..7
  const int ntl = p & 15;
  const int kh = dk & 3;
  const int tid = threadIdx.x;
  const int L = tid & 63, w = tid >> 6;
  const int wm = w & 1, wn = w >> 1;
  const int quad = L >> 4, lo = L & 15;

  __shared__ unsigned short As[128 * 32];
  __shared__ unsigned short Bs[128 * 32];

  const unsigned short* Ab = Xp + (size_t)kh * 1048576 + (size_t)mt * 128 * 1024;
  const unsigned short* Bb = Wb + (size_t)dk * 2097152 + (size_t)ntl * 128 * 1024;

  floatx4 acc[4][4] = {};

  for (int kc = 0; kc < 32; ++kc) {
#pragma unroll
    for (int ph = 0; ph < 2; ++ph) {
      int c = ph * 256 + w * 64 + L;
      int ldsb = (ph * 256 + w * 64) * 8;
      GLOAD_LDS16(Ab + (size_t)(c >> 2) * 1024 + kc * 32 + (c & 3) * 8, As + ldsb);
      GLOAD_LDS16(Bb + (size_t)(c >> 2) * 1024 + kc * 32 + (c & 3) * 8, Bs + ldsb);
    }
    __syncthreads();
    short8 af[4], bf[4];
#pragma unroll
    for (int mi = 0; mi < 4; ++mi)
      af[mi] = *(const short8*)(As + (wm * 64 + mi * 16 + lo) * 32 + quad * 8);
#pragma unroll
    for (int ni = 0; ni < 4; ++ni)
      bf[ni] = *(const short8*)(Bs + (wn * 64 + ni * 16 + lo) * 32 + quad * 8);
#pragma unroll
    for (int mi = 0; mi < 4; ++mi)
#pragma unroll
      for (int ni = 0; ni < 4; ++ni)
        acc[mi][ni] = __builtin_amdgcn_mfma_f32_16x16x32_bf16(af[mi], bf[ni], acc[mi][ni], 0, 0, 0);
    __syncthreads();
  }

  const float* bihp = (dk < 4) ? bihf : bihb;
  const float* bhhp = (dk < 4) ? bhhf : bhhb;
#pragma unroll
  for (int ni = 0; ni < 4; ++ni) {
    int g = ntl * 128 + wn * 64 + ni * 16 + lo;
    float bv = bihp[kh * 2048 + g] + bhhp[kh * 2048 + g];
#pragma unroll
    for (int mi = 0; mi < 4; ++mi)
#pragma unroll
      for (int r = 0; r < 4; ++r) {
        int m = mt * 128 + wm * 64 + mi * 16 + quad * 4 + r;
        ih[((size_t)dk * 1024 + m) * 2048 + g] = acc[mi][ni][r] + bv;
      }
  }
}

// NEW 256x256 GEMM (dk=0 partial rollout). 512 thr / 8 waves (2M x 4N),
// BK=64, dbuf 128KB LDS, stage-early + one __syncthreads per K-tile (T3
// minimal 2-phase), XOR slot swizzle: LDS slot s of row r holds global
// col-group s^(r&7); reads use slot (kk*4+quad)^(row&7) -> 2-way conflicts.
__global__ __launch_bounds__(512, 2) void gemm256_k(
    const unsigned short* __restrict__ Xp, const unsigned short* __restrict__ Wb,
    const float* __restrict__ bihf, const float* __restrict__ bhhf,
    float* __restrict__ ih) {
  const int mt = blockIdx.x & 3;   // 4 M-tiles of 256
  const int nt = blockIdx.x >> 2;  // 8 N-tiles of 256
  const int tid = threadIdx.x;
  const int L = tid & 63, w = tid >> 6;
  const int wm = w >> 2, wn = w & 3;  // 2 x 4 wave grid; wave out = 128x64
  const int quad = L >> 4, lo = L & 15;

  __shared__ unsigned short smem[65536];  // [2 buf][A 16384 | B 16384] shorts

  const unsigned short* Ab = Xp + (size_t)mt * 256 * 1024;  // kh=0 plane
  const unsigned short* Bb = Wb + (size_t)nt * 256 * 1024;  // dk=0

  floatx4 acc[8][4] = {};

#define STAGE256(t, buf)                                                     \
  do {                                                                       \
    unsigned short* SA = smem + (buf) * 32768;                               \
    unsigned short* SB = SA + 16384;                                         \
    _Pragma("unroll")                                                        \
    for (int j = 0; j < 4; ++j) {                                            \
      int c = j * 512 + tid;                                                 \
      int row = c >> 3;                                                      \
      int qs = (c & 7) ^ (row & 7);                                          \
      int ldsb = (j * 512 + w * 64) * 8; /* wave-uniform base (shorts) */    \
      GLOAD_LDS16(Ab + (size_t)row * 1024 + (t) * 64 + qs * 8, SA + ldsb);   \
      GLOAD_LDS16(Bb + (size_t)row * 1024 + (t) * 64 + qs * 8, SB + ldsb);   \
    }                                                                        \
  } while (0)

  STAGE256(0, 0);
  __syncthreads();

  for (int t = 0; t < 16; ++t) {
    if (t < 15) STAGE256(t + 1, (t + 1) & 1);  // issue early, overlaps MFMA
    const unsigned short* SA = smem + (t & 1) * 32768;
    const unsigned short* SB = SA + 16384;
#pragma unroll
    for (int kk = 0; kk < 2; ++kk) {
      short8 af[8], bf[4];
#pragma unroll
      for (int mi = 0; mi < 8; ++mi) {
        int row = wm * 128 + mi * 16 + lo;
        int slot = (kk * 4 + quad) ^ (row & 7);
        af[mi] = *(const short8*)(SA + row * 64 + slot * 8);
      }
#pragma unroll
      for (int ni = 0; ni < 4; ++ni) {
        int row = wn * 64 + ni * 16 + lo;
        int slot = (kk * 4 + quad) ^ (row & 7);
        bf[ni] = *(const short8*)(SB + row * 64 + slot * 8);
      }
#pragma unroll
      for (int mi = 0; mi < 8; ++mi)
#pragma unroll
        for (int ni = 0; ni < 4; ++ni)
          acc[mi][ni] = __builtin_amdgcn_mfma_f32_16x16x32_bf16(af[mi], bf[ni], acc[mi][ni], 0, 0, 0);
    }
    __syncthreads();  // stage(t+1) complete + LDS reads drained before reuse
  }

#pragma unroll
  for (int ni = 0; ni < 4; ++ni) {
    int g = nt * 256 + wn * 64 + ni * 16 + lo;
    float bv = bihf[g] + bhhf[g];  // dk=0 -> kh=0, forward biases
#pragma unroll
    for (int mi = 0; mi < 8; ++mi)
#pragma unroll
      for (int r = 0; r < 4; ++r) {
        int m = mt * 256 + wm * 128 + mi * 16 + quad * 4 + r;
        ih[(size_t)m * 2048 + g] = acc[mi][ni][r] + bv;  // dk=0 base
      }
  }
#undef STAGE256
}

// Persistent recurrence (R11 form, unchanged). grid=128: grp=bid&7, wg=bid>>3.
__global__ __launch_bounds__(256) void lstm_rec_k(
    const float* __restrict__ ih, const unsigned short* __restrict__ whh,
    float* __restrict__ out, ull* __restrict__ stateS) {
  const int tid = threadIdx.x;
  const int L = tid & 63;
  const int w = tid >> 6;
  const int grp = blockIdx.x & 7;
  const int d = grp >> 2, kh = grp & 3;
  const int wg = blockIdx.x >> 3;
  const int j0 = wg * 32;
  const int quad = L >> 4, lo = L & 15;

  __shared__ unsigned short h_lds[16 * 520];  // rows 8..15 stay zero (M-pad)
  __shared__ float gbuf[4][8][32];            // [gate][b][jj]

  for (int i = tid; i < 16 * 520; i += 256) h_lds[i] = 0;

  short8 bfrag[2][16];
#pragma unroll
  for (int ni = 0; ni < 2; ++ni) {
    const unsigned short* wb =
        whh + ((size_t)grp * 2048 + (size_t)(w * 512 + j0 + ni * 16 + lo)) * 512 + quad * 8;
#pragma unroll
    for (int kk = 0; kk < 16; ++kk) bfrag[ni][kk] = *(const short8*)(wb + kk * 32);
  }

  const int pb = tid >> 5, pjj = tid & 31;  // pointwise cell (b, jj)
  float creg = 0.0f;

  float ihv[2][4];
  {
    int t0 = d ? 127 : 0;
#pragma unroll
    for (int ni = 0; ni < 2; ++ni) {
      const float* ihp =
          ih + ((size_t)grp * 1024 + (size_t)t0 * 8) * 2048 + (w * 512 + j0 + ni * 16 + lo);
#pragma unroll
      for (int r = 0; r < 4; ++r) {
        int b = quad * 4 + r;
        ihv[ni][r] = (b < 8) ? ihp[(size_t)b * 2048] : 0.0f;
      }
    }
  }

  const int srow = tid >> 5;
  const int scol = (tid & 31) * 16;

  for (int s = 0; s < 128; ++s) {
    const int t = d ? (127 - s) : s;

    // R11: issue ih prefetch for s+1 FIRST; hides under the poll wait.
    float ihvN[2][4];
    if (s < 127) {
      int tn = d ? (126 - s) : (s + 1);
#pragma unroll
      for (int ni = 0; ni < 2; ++ni) {
        const float* ihp =
            ih + ((size_t)grp * 1024 + (size_t)tn * 8) * 2048 + (w * 512 + j0 + ni * 16 + lo);
#pragma unroll
        for (int r = 0; r < 4; ++r) {
          int b = quad * 4 + r;
          ihvN[ni][r] = (b < 8) ? ihp[(size_t)b * 2048] : 0.0f;
        }
      }
    } else {
#pragma unroll
      for (int ni = 0; ni < 2; ++ni)
#pragma unroll
        for (int r = 0; r < 4; ++r) ihvN[ni][r] = 0.0f;
    }

    if (s) {
      const ull* src = stateS + ((size_t)grp * 128 + s) * 1024 + tid * 4;
      ull v0, v1, v2, v3;
      do {
        v0 = __hip_atomic_load(src + 0, __ATOMIC_RELAXED, __HIP_MEMORY_SCOPE_AGENT);
        v1 = __hip_atomic_load(src + 1, __ATOMIC_RELAXED, __HIP_MEMORY_SCOPE_AGENT);
        v2 = __hip_atomic_load(src + 2, __ATOMIC_RELAXED, __HIP_MEMORY_SCOPE_AGENT);
        v3 = __hip_atomic_load(src + 3, __ATOMIC_RELAXED, __HIP_MEMORY_SCOPE_AGENT);
      } while (v0 == POISON || v1 == POISON || v2 == POISON || v3 == POISON);
      unsigned short* dl = h_lds + srow * 520 + scol;
      *(ull*)(dl + 0) = v0;
      *(ull*)(dl + 4) = v1;
      *(ull*)(dl + 8) = v2;
      *(ull*)(dl + 12) = v3;
    }
    LDS_BARRIER();

    floatx4 acc[2] = {};
    floatx4 acc2[2] = {};
    {
      const unsigned short* ar = h_lds + lo * 520 + quad * 8;
#pragma unroll
      for (int kk = 0; kk < 16; kk += 2) {
        short8 a0 = *(const short8*)(ar + kk * 32);
        short8 a1 = *(const short8*)(ar + (kk + 1) * 32);
#pragma unroll
        for (int ni = 0; ni < 2; ++ni) {
          acc[ni]  = __builtin_amdgcn_mfma_f32_16x16x32_bf16(a0, bfrag[ni][kk], acc[ni], 0, 0, 0);
          acc2[ni] = __builtin_amdgcn_mfma_f32_16x16x32_bf16(a1, bfrag[ni][kk + 1], acc2[ni], 0, 0, 0);
        }
      }
    }
#pragma unroll
    for (int ni = 0; ni < 2; ++ni)
#pragma unroll
      for (int r = 0; r < 4; ++r) {
        int b = quad * 4 + r;
        if (b < 8) gbuf[w][b][ni * 16 + lo] = acc[ni][r] + acc2[ni][r] + ihv[ni][r];
      }
    LDS_BARRIER();

    {
      float ig = gbuf[0][pb][pjj], fg = gbuf[1][pb][pjj];
      float gg = gbuf[2][pb][pjj], og = gbuf[3][pb][pjj];
      float cn = sigm(fg) * creg + sigm(ig) * tanh_f(gg);
      creg = cn;
      float h = sigm(og) * tanh_f(cn);

      if (s < 127) {
        unsigned hs = f2bf(h);
        int base = L & ~3;
        unsigned v0 = __shfl(hs, base + 0);
        unsigned v1 = __shfl(hs, base + 1);
        unsigned v2 = __shfl(hs, base + 2);
        unsigned v3 = __shfl(hs, base + 3);
        if ((L & 3) == 0) {
          ull wv = (ull)v0 | ((ull)v1 << 16) | ((ull)v2 << 32) | ((ull)v3 << 48);
          ull* dst = stateS + ((size_t)grp * 128 + (s + 1)) * 1024 + pb * 128 + ((j0 + pjj) >> 2);
          __hip_atomic_store(dst, wv, __ATOMIC_RELAXED, __HIP_MEMORY_SCOPE_AGENT);
        }
      }
      out[(((size_t)pb * 128 + t) * 1024 + d * 512 + j0 + pjj) * 4 + kh] = h;
    }

#pragma unroll
    for (int ni = 0; ni < 2; ++ni)
#pragma unroll
      for (int r = 0; r < 4; ++r) ihv[ni][r] = ihvN[ni][r];
  }
}

extern "C" void kernel_launch(void* const* d_in, const int* in_sizes, int n_in,
                              void* d_out, int out_size, void* d_ws, size_t ws_size,
                              hipStream_t stream) {
  (void)in_sizes; (void)n_in; (void)out_size; (void)ws_size;
  const float* x     = (const float*)d_in[0];
  const float* Wih_f = (const float*)d_in[1];
  const float* Whh_f = (const float*)d_in[2];
  const float* bih_f = (const float*)d_in[3];
  const float* bhh_f = (const float*)d_in[4];
  const float* Wih_b = (const float*)d_in[5];
  const float* Whh_b = (const float*)d_in[6];
  const float* bih_b = (const float*)d_in[7];
  const float* bhh_b = (const float*)d_in[8];
  float* out = (float*)d_out;
  char* ws = (char*)d_ws;

  ull* stateS          = (ull*)ws;                               // 8 MB
  float* ihg           = (float*)(ws + (8ull << 20));            // 64 MB
  unsigned short* Xp   = (unsigned short*)(ws + (72ull << 20));  // 8 MB
  unsigned short* Wihb = (unsigned short*)(ws + (80ull << 20));  // 32 MB
  unsigned short* Whhb = (unsigned short*)(ws + (112ull << 20)); // 16 MB

  prep_k<<<29696, 256, 0, stream>>>(x, Wih_f, Wih_b, Whh_f, Whh_b, Xp, Wihb, Whhb, stateS);
  gemm_ih_k<<<896, 256, 0, stream>>>(Xp, Wihb, bih_f, bhh_f, bih_b, bhh_b, ihg);   // dk 1..7
  gemm256_k<<<32, 512, 0, stream>>>(Xp, Wihb, bih_f, bhh_f, ihg);                  // dk 0
  lstm_rec_k<<<128, 256, 0, stream>>>(ihg, Whhb, out, stateS);
}

// Round 9
// 401.527 us; speedup vs baseline: 1.0987x; 1.0987x over previous
//
#include <hip/hip_runtime.h>
#include <stdint.h>

// Multi_LSTMs: bidirectional 4-head LSTM, BS=8 NT=128 CH=1024 H=512 G=2048.
// R1-R4: poison-poll state exchange, no fences in step loop.
// R5: MFMA split into 2 chains. R6 FAILED fusion. R7 FAILED bundle.
// R8 REFUTED residency. R9 REFUTED spin-traffic.
// R10: LDS_BARRIER (no vmcnt drain) -12us.
// R11 CONFIRMED: loop-top ih prefetch hides under poll wait; rec 266->216us.
// R12: partial 256^2 rollout (dk=0): correctness PASSED; priced the block at
//   ~52us (2.5 TF/CU, wall = per-block time since 1 pass). Total +22 as the
//   partial was serialized -- expected; it was a measurement round.
// R13 (this round): FULL swap to gemm256_k (all 8 dk, 256 blocks = exactly
//   one pass over 256 CUs). Old m97 gemm deleted. Whole ih-GEMM ~55us vs
//   ~183us serialized in R12 / ~150us in R7. bid = mt*64 + dk*8 + nt ->
//   same-B-panel blocks share an XCD (4MB B-panels/XCD = L2-resident).

typedef __attribute__((ext_vector_type(8))) short short8;
typedef __attribute__((ext_vector_type(4))) float floatx4;
typedef unsigned long long ull;

#define POISON 0x7FC07FC07FC07FC0ull  // 4 x bf16 NaN (stateS)

// Barrier WITHOUT the implicit vmcnt(0) drain: only LDS ops must be visible.
#define LDS_BARRIER()                                       \
  do {                                                      \
    asm volatile("s_waitcnt lgkmcnt(0)" ::: "memory");      \
    __builtin_amdgcn_s_barrier();                           \
  } while (0)

#define GLOAD_LDS16(g, l)                                        \
  __builtin_amdgcn_global_load_lds(                              \
      (const __attribute__((address_space(1))) void*)(g),        \
      (__attribute__((address_space(3))) void*)(l), 16, 0, 0)

__device__ __forceinline__ unsigned short f2bf(float f) {
  unsigned u = __float_as_uint(f);
  u = (u + 0x7fffu + ((u >> 16) & 1u)) >> 16;  // RNE
  return (unsigned short)u;
}
__device__ __forceinline__ float sigm(float x) { return 1.0f / (1.0f + __expf(-x)); }
__device__ __forceinline__ float tanh_f(float x) {
  float ax = fabsf(x);
  float e = __expf(-2.0f * ax);
  float t = (1.0f - e) / (1.0f + e);
  return x < 0.0f ? -t : t;
}

// One prep kernel: pack x (4-wide), cast weights to bf16, poison stateS.
// Work items: pack 262144 | Wih_f 2M | Wih_b 2M | Whh_f 1M | Whh_b 1M | stateS 1M
__global__ __launch_bounds__(256) void prep_k(
    const float* __restrict__ x,
    const float* __restrict__ Wih_f, const float* __restrict__ Wih_b,
    const float* __restrict__ Whh_f, const float* __restrict__ Whh_b,
    unsigned short* __restrict__ Xp, unsigned short* __restrict__ Wihb,
    unsigned short* __restrict__ Whhb, ull* __restrict__ stateS) {
  size_t i = (size_t)blockIdx.x * 256 + threadIdx.x;
  if (i < 262144) {  // pack x: thread = (m, 4 consecutive c); 8B stores per kh
    int m = (int)i >> 8, cb = (int)i & 255;
    int t = m >> 3, b = m & 7;
    const float* xs = x + ((size_t)((b * 128 + t) * 1024 + cb * 4)) * 4;
    float4 v0 = ((const float4*)xs)[0];
    float4 v1 = ((const float4*)xs)[1];
    float4 v2 = ((const float4*)xs)[2];
    float4 v3 = ((const float4*)xs)[3];
    int o = m * 1024 + cb * 4;  // element offset within a kh-plane
    ushort4 o0 = {f2bf(v0.x), f2bf(v1.x), f2bf(v2.x), f2bf(v3.x)};
    ushort4 o1 = {f2bf(v0.y), f2bf(v1.y), f2bf(v2.y), f2bf(v3.y)};
    ushort4 o2 = {f2bf(v0.z), f2bf(v1.z), f2bf(v2.z), f2bf(v3.z)};
    ushort4 o3 = {f2bf(v0.w), f2bf(v1.w), f2bf(v2.w), f2bf(v3.w)};
    *(ushort4*)(Xp + o)           = o0;
    *(ushort4*)(Xp + 1048576 + o) = o1;
    *(ushort4*)(Xp + 2097152 + o) = o2;
    *(ushort4*)(Xp + 3145728 + o) = o3;
  } else if (i < 2359296) {  // Wih_f: 2M float4
    size_t j = i - 262144;
    float4 v = ((const float4*)Wih_f)[j];
    ushort4 o;
    o.x = f2bf(v.x); o.y = f2bf(v.y); o.z = f2bf(v.z); o.w = f2bf(v.w);
    ((ushort4*)Wihb)[j] = o;
  } else if (i < 4456448) {  // Wih_b
    size_t j = i - 2359296;
    float4 v = ((const float4*)Wih_b)[j];
    ushort4 o;
    o.x = f2bf(v.x); o.y = f2bf(v.y); o.z = f2bf(v.z); o.w = f2bf(v.w);
    ((ushort4*)Wihb)[2097152 + j] = o;
  } else if (i < 5505024) {  // Whh_f: 1M float4
    size_t j = i - 4456448;
    float4 v = ((const float4*)Whh_f)[j];
    ushort4 o;
    o.x = f2bf(v.x); o.y = f2bf(v.y); o.z = f2bf(v.z); o.w = f2bf(v.w);
    ((ushort4*)Whhb)[j] = o;
  } else if (i < 6553600) {  // Whh_b
    size_t j = i - 5505024;
    float4 v = ((const float4*)Whh_b)[j];
    ushort4 o;
    o.x = f2bf(v.x); o.y = f2bf(v.y); o.z = f2bf(v.z); o.w = f2bf(v.w);
    ((ushort4*)Whhb)[1048576 + j] = o;
  } else {  // stateS poison: 1M ull
    stateS[i - 6553600] = POISON;
  }
}

// 256x256 BK=64 dbuf GEMM, ALL dk (R12-verified structure). 512 thr / 8 waves
// (2M x 4N), stage-early + one __syncthreads per K-tile, XOR slot swizzle
// (slot s of row r holds global col-group s^(r&7)).
// bid = mt*64 + dk*8 + nt: same-B-panel blocks (4 mt) share bid%8 -> same XCD;
// per-XCD B working set = 8 panels x 512KB = 4MB = L2.
__global__ __launch_bounds__(512, 2) void gemm256_k(
    const unsigned short* __restrict__ Xp, const unsigned short* __restrict__ Wb,
    const float* __restrict__ bihf, const float* __restrict__ bhhf,
    const float* __restrict__ bihb, const float* __restrict__ bhhb,
    float* __restrict__ ih) {
  const int bid = blockIdx.x;
  const int mt = bid >> 6;         // 0..3
  const int pn = bid & 63;
  const int dk = pn >> 3;          // 0..7
  const int nt = pn & 7;           // 0..7
  const int kh = dk & 3;
  const int tid = threadIdx.x;
  const int L = tid & 63, w = tid >> 6;
  const int wm = w >> 2, wn = w & 3;  // 2 x 4 wave grid; wave out = 128x64
  const int quad = L >> 4, lo = L & 15;

  __shared__ unsigned short smem[65536];  // [2 buf][A 32KB | B 32KB]

  const unsigned short* Ab = Xp + (size_t)kh * 1048576 + (size_t)mt * 256 * 1024;
  const unsigned short* Bb = Wb + (size_t)dk * 2097152 + (size_t)nt * 256 * 1024;

  floatx4 acc[8][4] = {};

#define STAGE256(t, buf)                                                     \
  do {                                                                       \
    unsigned short* SA = smem + (buf) * 32768;                               \
    unsigned short* SB = SA + 16384;                                         \
    _Pragma("unroll")                                                        \
    for (int j = 0; j < 4; ++j) {                                            \
      int c = j * 512 + tid;                                                 \
      int row = c >> 3;                                                      \
      int qs = (c & 7) ^ (row & 7);                                          \
      int ldsb = (j * 512 + w * 64) * 8; /* wave-uniform base (shorts) */    \
      GLOAD_LDS16(Ab + (size_t)row * 1024 + (t) * 64 + qs * 8, SA + ldsb);   \
      GLOAD_LDS16(Bb + (size_t)row * 1024 + (t) * 64 + qs * 8, SB + ldsb);   \
    }                                                                        \
  } while (0)

  STAGE256(0, 0);
  __syncthreads();

  for (int t = 0; t < 16; ++t) {
    if (t < 15) STAGE256(t + 1, (t + 1) & 1);  // issue early, overlaps MFMA
    const unsigned short* SA = smem + (t & 1) * 32768;
    const unsigned short* SB = SA + 16384;
#pragma unroll
    for (int kk = 0; kk < 2; ++kk) {
      short8 af[8], bf[4];
#pragma unroll
      for (int mi = 0; mi < 8; ++mi) {
        int row = wm * 128 + mi * 16 + lo;
        int slot = (kk * 4 + quad) ^ (row & 7);
        af[mi] = *(const short8*)(SA + row * 64 + slot * 8);
      }
#pragma unroll
      for (int ni = 0; ni < 4; ++ni) {
        int row = wn * 64 + ni * 16 + lo;
        int slot = (kk * 4 + quad) ^ (row & 7);
        bf[ni] = *(const short8*)(SB + row * 64 + slot * 8);
      }
#pragma unroll
      for (int mi = 0; mi < 8; ++mi)
#pragma unroll
        for (int ni = 0; ni < 4; ++ni)
          acc[mi][ni] = __builtin_amdgcn_mfma_f32_16x16x32_bf16(af[mi], bf[ni], acc[mi][ni], 0, 0, 0);
    }
    __syncthreads();  // stage(t+1) complete + LDS reads drained before reuse
  }

  const float* bihp = (dk < 4) ? bihf : bihb;
  const float* bhhp = (dk < 4) ? bhhf : bhhb;
#pragma unroll
  for (int ni = 0; ni < 4; ++ni) {
    int g = nt * 256 + wn * 64 + ni * 16 + lo;
    float bv = bihp[kh * 2048 + g] + bhhp[kh * 2048 + g];
#pragma unroll
    for (int mi = 0; mi < 8; ++mi)
#pragma unroll
      for (int r = 0; r < 4; ++r) {
        int m = mt * 256 + wm * 128 + mi * 16 + quad * 4 + r;
        ih[((size_t)dk * 1024 + m) * 2048 + g] = acc[mi][ni][r] + bv;
      }
  }
#undef STAGE256
}

// Persistent recurrence (R11 form, unchanged). grid=128: grp=bid&7, wg=bid>>3.
__global__ __launch_bounds__(256) void lstm_rec_k(
    const float* __restrict__ ih, const unsigned short* __restrict__ whh,
    float* __restrict__ out, ull* __restrict__ stateS) {
  const int tid = threadIdx.x;
  const int L = tid & 63;
  const int w = tid >> 6;
  const int grp = blockIdx.x & 7;
  const int d = grp >> 2, kh = grp & 3;
  const int wg = blockIdx.x >> 3;
  const int j0 = wg * 32;
  const int quad = L >> 4, lo = L & 15;

  __shared__ unsigned short h_lds[16 * 520];  // rows 8..15 stay zero (M-pad)
  __shared__ float gbuf[4][8][32];            // [gate][b][jj]

  for (int i = tid; i < 16 * 520; i += 256) h_lds[i] = 0;

  short8 bfrag[2][16];
#pragma unroll
  for (int ni = 0; ni < 2; ++ni) {
    const unsigned short* wb =
        whh + ((size_t)grp * 2048 + (size_t)(w * 512 + j0 + ni * 16 + lo)) * 512 + quad * 8;
#pragma unroll
    for (int kk = 0; kk < 16; ++kk) bfrag[ni][kk] = *(const short8*)(wb + kk * 32);
  }

  const int pb = tid >> 5, pjj = tid & 31;  // pointwise cell (b, jj)
  float creg = 0.0f;

  float ihv[2][4];
  {
    int t0 = d ? 127 : 0;
#pragma unroll
    for (int ni = 0; ni < 2; ++ni) {
      const float* ihp =
          ih + ((size_t)grp * 1024 + (size_t)t0 * 8) * 2048 + (w * 512 + j0 + ni * 16 + lo);
#pragma unroll
      for (int r = 0; r < 4; ++r) {
        int b = quad * 4 + r;
        ihv[ni][r] = (b < 8) ? ihp[(size_t)b * 2048] : 0.0f;
      }
    }
  }

  const int srow = tid >> 5;
  const int scol = (tid & 31) * 16;

  for (int s = 0; s < 128; ++s) {
    const int t = d ? (127 - s) : s;

    // R11: issue ih prefetch for s+1 FIRST; hides under the poll wait.
    float ihvN[2][4];
    if (s < 127) {
      int tn = d ? (126 - s) : (s + 1);
#pragma unroll
      for (int ni = 0; ni < 2; ++ni) {
        const float* ihp =
            ih + ((size_t)grp * 1024 + (size_t)tn * 8) * 2048 + (w * 512 + j0 + ni * 16 + lo);
#pragma unroll
        for (int r = 0; r < 4; ++r) {
          int b = quad * 4 + r;
          ihvN[ni][r] = (b < 8) ? ihp[(size_t)b * 2048] : 0.0f;
        }
      }
    } else {
#pragma unroll
      for (int ni = 0; ni < 2; ++ni)
#pragma unroll
        for (int r = 0; r < 4; ++r) ihvN[ni][r] = 0.0f;
    }

    if (s) {
      const ull* src = stateS + ((size_t)grp * 128 + s) * 1024 + tid * 4;
      ull v0, v1, v2, v3;
      do {
        v0 = __hip_atomic_load(src + 0, __ATOMIC_RELAXED, __HIP_MEMORY_SCOPE_AGENT);
        v1 = __hip_atomic_load(src + 1, __ATOMIC_RELAXED, __HIP_MEMORY_SCOPE_AGENT);
        v2 = __hip_atomic_load(src + 2, __ATOMIC_RELAXED, __HIP_MEMORY_SCOPE_AGENT);
        v3 = __hip_atomic_load(src + 3, __ATOMIC_RELAXED, __HIP_MEMORY_SCOPE_AGENT);
      } while (v0 == POISON || v1 == POISON || v2 == POISON || v3 == POISON);
      unsigned short* dl = h_lds + srow * 520 + scol;
      *(ull*)(dl + 0) = v0;
      *(ull*)(dl + 4) = v1;
      *(ull*)(dl + 8) = v2;
      *(ull*)(dl + 12) = v3;
    }
    LDS_BARRIER();

    floatx4 acc[2] = {};
    floatx4 acc2[2] = {};
    {
      const unsigned short* ar = h_lds + lo * 520 + quad * 8;
#pragma unroll
      for (int kk = 0; kk < 16; kk += 2) {
        short8 a0 = *(const short8*)(ar + kk * 32);
        short8 a1 = *(const short8*)(ar + (kk + 1) * 32);
#pragma unroll
        for (int ni = 0; ni < 2; ++ni) {
          acc[ni]  = __builtin_amdgcn_mfma_f32_16x16x32_bf16(a0, bfrag[ni][kk], acc[ni], 0, 0, 0);
          acc2[ni] = __builtin_amdgcn_mfma_f32_16x16x32_bf16(a1, bfrag[ni][kk + 1], acc2[ni], 0, 0, 0);
        }
      }
    }
#pragma unroll
    for (int ni = 0; ni < 2; ++ni)
#pragma unroll
      for (int r = 0; r < 4; ++r) {
        int b = quad * 4 + r;
        if (b < 8) gbuf[w][b][ni * 16 + lo] = acc[ni][r] + acc2[ni][r] + ihv[ni][r];
      }
    LDS_BARRIER();

    {
      float ig = gbuf[0][pb][pjj], fg = gbuf[1][pb][pjj];
      float gg = gbuf[2][pb][pjj], og = gbuf[3][pb][pjj];
      float cn = sigm(fg) * creg + sigm(ig) * tanh_f(gg);
      creg = cn;
      float h = sigm(og) * tanh_f(cn);

      if (s < 127) {
        unsigned hs = f2bf(h);
        int base = L & ~3;
        unsigned v0 = __shfl(hs, base + 0);
        unsigned v1 = __shfl(hs, base + 1);
        unsigned v2 = __shfl(hs, base + 2);
        unsigned v3 = __shfl(hs, base + 3);
        if ((L & 3) == 0) {
          ull wv = (ull)v0 | ((ull)v1 << 16) | ((ull)v2 << 32) | ((ull)v3 << 48);
          ull* dst = stateS + ((size_t)grp * 128 + (s + 1)) * 1024 + pb * 128 + ((j0 + pjj) >> 2);
          __hip_atomic_store(dst, wv, __ATOMIC_RELAXED, __HIP_MEMORY_SCOPE_AGENT);
        }
      }
      out[(((size_t)pb * 128 + t) * 1024 + d * 512 + j0 + pjj) * 4 + kh] = h;
    }

#pragma unroll
    for (int ni = 0; ni < 2; ++ni)
#pragma unroll
      for (int r = 0; r < 4; ++r) ihv[ni][r] = ihvN[ni][r];
  }
}

extern "C" void kernel_launch(void* const* d_in, const int* in_sizes, int n_in,
                              void* d_out, int out_size, void* d_ws, size_t ws_size,
                              hipStream_t stream) {
  (void)in_sizes; (void)n_in; (void)out_size; (void)ws_size;
  const float* x     = (const float*)d_in[0];
  const float* Wih_f = (const float*)d_in[1];
  const float* Whh_f = (const float*)d_in[2];
  const float* bih_f = (const float*)d_in[3];
  const float* bhh_f = (const float*)d_in[4];
  const float* Wih_b = (const float*)d_in[5];
  const float* Whh_b = (const float*)d_in[6];
  const float* bih_b = (const float*)d_in[7];
  const float* bhh_b = (const float*)d_in[8];
  float* out = (float*)d_out;
  char* ws = (char*)d_ws;

  ull* stateS          = (ull*)ws;                               // 8 MB
  float* ihg           = (float*)(ws + (8ull << 20));            // 64 MB
  unsigned short* Xp   = (unsigned short*)(ws + (72ull << 20));  // 8 MB
  unsigned short* Wihb = (unsigned short*)(ws + (80ull << 20));  // 32 MB
  unsigned short* Whhb = (unsigned short*)(ws + (112ull << 20)); // 16 MB

  prep_k<<<29696, 256, 0, stream>>>(x, Wih_f, Wih_b, Whh_f, Whh_b, Xp, Wihb, Whhb, stateS);
  gemm256_k<<<256, 512, 0, stream>>>(Xp, Wihb, bih_f, bhh_f, bih_b, bhh_b, ihg);
  lstm_rec_k<<<128, 256, 0, stream>>>(ihg, Whhb, out, stateS);
}

// Round 10
// 401.241 us; speedup vs baseline: 1.0995x; 1.0007x over previous
//
#include <hip/hip_runtime.h>
#include <stdint.h>

// Multi_LSTMs: bidirectional 4-head LSTM, BS=8 NT=128 CH=1024 H=512 G=2048.
// R1-R4: poison-poll state exchange, no fences in step loop.
// R5: MFMA split into 2 chains. R6 FAILED fusion. R7 FAILED bundle.
// R8 REFUTED residency. R9 REFUTED spin-traffic.
// R10: LDS_BARRIER (no vmcnt drain) -12us.
// R11 CONFIRMED: loop-top ih prefetch hides under poll wait; rec 266->216us.
// R12: partial 256^2 rollout: priced g256 at ~40us for 1/8 grid.
// R13: full swap: -17us only. g256_full ~115-132us = 260 TF = 131 FLOP/B x
//   ~2 TB/s -> STAGING-BW-BOUND. Cause: bid%8 = nt mapping -> per-XCD WS =
//   12 MB (A 8 + B 4) >> 4 MB L2 -> thrash -> 256 MB amplified traffic at
//   LLC/HBM speed.
// R14 (this round): ONE LINE -- remap XCD = dk (bid = dk + 8*(mt*8+nt)).
//   Per-XCD WS = 6 MB, active per-K-tile slab = 384 KB -> L2 captures the
//   4x/8x cross-block reuse; unique fetch ~48 MB. Everything else untouched.

typedef __attribute__((ext_vector_type(8))) short short8;
typedef __attribute__((ext_vector_type(4))) float floatx4;
typedef unsigned long long ull;

#define POISON 0x7FC07FC07FC07FC0ull  // 4 x bf16 NaN (stateS)

// Barrier WITHOUT the implicit vmcnt(0) drain: only LDS ops must be visible.
#define LDS_BARRIER()                                       \
  do {                                                      \
    asm volatile("s_waitcnt lgkmcnt(0)" ::: "memory");      \
    __builtin_amdgcn_s_barrier();                           \
  } while (0)

#define GLOAD_LDS16(g, l)                                        \
  __builtin_amdgcn_global_load_lds(                              \
      (const __attribute__((address_space(1))) void*)(g),        \
      (__attribute__((address_space(3))) void*)(l), 16, 0, 0)

__device__ __forceinline__ unsigned short f2bf(float f) {
  unsigned u = __float_as_uint(f);
  u = (u + 0x7fffu + ((u >> 16) & 1u)) >> 16;  // RNE
  return (unsigned short)u;
}
__device__ __forceinline__ float sigm(float x) { return 1.0f / (1.0f + __expf(-x)); }
__device__ __forceinline__ float tanh_f(float x) {
  float ax = fabsf(x);
  float e = __expf(-2.0f * ax);
  float t = (1.0f - e) / (1.0f + e);
  return x < 0.0f ? -t : t;
}

// One prep kernel: pack x (4-wide), cast weights to bf16, poison stateS.
__global__ __launch_bounds__(256) void prep_k(
    const float* __restrict__ x,
    const float* __restrict__ Wih_f, const float* __restrict__ Wih_b,
    const float* __restrict__ Whh_f, const float* __restrict__ Whh_b,
    unsigned short* __restrict__ Xp, unsigned short* __restrict__ Wihb,
    unsigned short* __restrict__ Whhb, ull* __restrict__ stateS) {
  size_t i = (size_t)blockIdx.x * 256 + threadIdx.x;
  if (i < 262144) {  // pack x: thread = (m, 4 consecutive c); 8B stores per kh
    int m = (int)i >> 8, cb = (int)i & 255;
    int t = m >> 3, b = m & 7;
    const float* xs = x + ((size_t)((b * 128 + t) * 1024 + cb * 4)) * 4;
    float4 v0 = ((const float4*)xs)[0];
    float4 v1 = ((const float4*)xs)[1];
    float4 v2 = ((const float4*)xs)[2];
    float4 v3 = ((const float4*)xs)[3];
    int o = m * 1024 + cb * 4;  // element offset within a kh-plane
    ushort4 o0 = {f2bf(v0.x), f2bf(v1.x), f2bf(v2.x), f2bf(v3.x)};
    ushort4 o1 = {f2bf(v0.y), f2bf(v1.y), f2bf(v2.y), f2bf(v3.y)};
    ushort4 o2 = {f2bf(v0.z), f2bf(v1.z), f2bf(v2.z), f2bf(v3.z)};
    ushort4 o3 = {f2bf(v0.w), f2bf(v1.w), f2bf(v2.w), f2bf(v3.w)};
    *(ushort4*)(Xp + o)           = o0;
    *(ushort4*)(Xp + 1048576 + o) = o1;
    *(ushort4*)(Xp + 2097152 + o) = o2;
    *(ushort4*)(Xp + 3145728 + o) = o3;
  } else if (i < 2359296) {  // Wih_f: 2M float4
    size_t j = i - 262144;
    float4 v = ((const float4*)Wih_f)[j];
    ushort4 o;
    o.x = f2bf(v.x); o.y = f2bf(v.y); o.z = f2bf(v.z); o.w = f2bf(v.w);
    ((ushort4*)Wihb)[j] = o;
  } else if (i < 4456448) {  // Wih_b
    size_t j = i - 2359296;
    float4 v = ((const float4*)Wih_b)[j];
    ushort4 o;
    o.x = f2bf(v.x); o.y = f2bf(v.y); o.z = f2bf(v.z); o.w = f2bf(v.w);
    ((ushort4*)Wihb)[2097152 + j] = o;
  } else if (i < 5505024) {  // Whh_f: 1M float4
    size_t j = i - 4456448;
    float4 v = ((const float4*)Whh_f)[j];
    ushort4 o;
    o.x = f2bf(v.x); o.y = f2bf(v.y); o.z = f2bf(v.z); o.w = f2bf(v.w);
    ((ushort4*)Whhb)[j] = o;
  } else if (i < 6553600) {  // Whh_b
    size_t j = i - 5505024;
    float4 v = ((const float4*)Whh_b)[j];
    ushort4 o;
    o.x = f2bf(v.x); o.y = f2bf(v.y); o.z = f2bf(v.z); o.w = f2bf(v.w);
    ((ushort4*)Whhb)[1048576 + j] = o;
  } else {  // stateS poison: 1M ull
    stateS[i - 6553600] = POISON;
  }
}

// 256x256 BK=64 dbuf GEMM, ALL dk. 512 thr / 8 waves (2M x 4N), stage-early +
// one __syncthreads per K-tile, XOR slot swizzle.
// R14 mapping: bid = dk + 8*(mt*8 + nt) -> XCD (bid%8) = dk. Per-XCD unique
// WS = B(dk) 4MB + A(kh) 2MB; active K-slab 384KB -> L2-captured reuse.
__global__ __launch_bounds__(512, 2) void gemm256_k(
    const unsigned short* __restrict__ Xp, const unsigned short* __restrict__ Wb,
    const float* __restrict__ bihf, const float* __restrict__ bhhf,
    const float* __restrict__ bihb, const float* __restrict__ bhhb,
    float* __restrict__ ih) {
  const int bid = blockIdx.x;
  const int dk = bid & 7;          // XCD-pinned
  const int q  = bid >> 3;         // 0..31
  const int mt = q >> 3;           // 0..3
  const int nt = q & 7;            // 0..7
  const int kh = dk & 3;
  const int tid = threadIdx.x;
  const int L = tid & 63, w = tid >> 6;
  const int wm = w >> 2, wn = w & 3;  // 2 x 4 wave grid; wave out = 128x64
  const int quad = L >> 4, lo = L & 15;

  __shared__ unsigned short smem[65536];  // [2 buf][A 32KB | B 32KB]

  const unsigned short* Ab = Xp + (size_t)kh * 1048576 + (size_t)mt * 256 * 1024;
  const unsigned short* Bb = Wb + (size_t)dk * 2097152 + (size_t)nt * 256 * 1024;

  floatx4 acc[8][4] = {};

#define STAGE256(t, buf)                                                     \
  do {                                                                       \
    unsigned short* SA = smem + (buf) * 32768;                               \
    unsigned short* SB = SA + 16384;                                         \
    _Pragma("unroll")                                                        \
    for (int j = 0; j < 4; ++j) {                                            \
      int c = j * 512 + tid;                                                 \
      int row = c >> 3;                                                      \
      int qs = (c & 7) ^ (row & 7);                                          \
      int ldsb = (j * 512 + w * 64) * 8; /* wave-uniform base (shorts) */    \
      GLOAD_LDS16(Ab + (size_t)row * 1024 + (t) * 64 + qs * 8, SA + ldsb);   \
      GLOAD_LDS16(Bb + (size_t)row * 1024 + (t) * 64 + qs * 8, SB + ldsb);   \
    }                                                                        \
  } while (0)

  STAGE256(0, 0);
  __syncthreads();

  for (int t = 0; t < 16; ++t) {
    if (t < 15) STAGE256(t + 1, (t + 1) & 1);  // issue early, overlaps MFMA
    const unsigned short* SA = smem + (t & 1) * 32768;
    const unsigned short* SB = SA + 16384;
#pragma unroll
    for (int kk = 0; kk < 2; ++kk) {
      short8 af[8], bf[4];
#pragma unroll
      for (int mi = 0; mi < 8; ++mi) {
        int row = wm * 128 + mi * 16 + lo;
        int slot = (kk * 4 + quad) ^ (row & 7);
        af[mi] = *(const short8*)(SA + row * 64 + slot * 8);
      }
#pragma unroll
      for (int ni = 0; ni < 4; ++ni) {
        int row = wn * 64 + ni * 16 + lo;
        int slot = (kk * 4 + quad) ^ (row & 7);
        bf[ni] = *(const short8*)(SB + row * 64 + slot * 8);
      }
#pragma unroll
      for (int mi = 0; mi < 8; ++mi)
#pragma unroll
        for (int ni = 0; ni < 4; ++ni)
          acc[mi][ni] = __builtin_amdgcn_mfma_f32_16x16x32_bf16(af[mi], bf[ni], acc[mi][ni], 0, 0, 0);
    }
    __syncthreads();  // stage(t+1) complete + LDS reads drained before reuse
  }

  const float* bihp = (dk < 4) ? bihf : bihb;
  const float* bhhp = (dk < 4) ? bhhf : bhhb;
#pragma unroll
  for (int ni = 0; ni < 4; ++ni) {
    int g = nt * 256 + wn * 64 + ni * 16 + lo;
    float bv = bihp[kh * 2048 + g] + bhhp[kh * 2048 + g];
#pragma unroll
    for (int mi = 0; mi < 8; ++mi)
#pragma unroll
      for (int r = 0; r < 4; ++r) {
        int m = mt * 256 + wm * 128 + mi * 16 + quad * 4 + r;
        ih[((size_t)dk * 1024 + m) * 2048 + g] = acc[mi][ni][r] + bv;
      }
  }
#undef STAGE256
}

// Persistent recurrence (R11 form, unchanged). grid=128: grp=bid&7, wg=bid>>3.
__global__ __launch_bounds__(256) void lstm_rec_k(
    const float* __restrict__ ih, const unsigned short* __restrict__ whh,
    float* __restrict__ out, ull* __restrict__ stateS) {
  const int tid = threadIdx.x;
  const int L = tid & 63;
  const int w = tid >> 6;
  const int grp = blockIdx.x & 7;
  const int d = grp >> 2, kh = grp & 3;
  const int wg = blockIdx.x >> 3;
  const int j0 = wg * 32;
  const int quad = L >> 4, lo = L & 15;

  __shared__ unsigned short h_lds[16 * 520];  // rows 8..15 stay zero (M-pad)
  __shared__ float gbuf[4][8][32];            // [gate][b][jj]

  for (int i = tid; i < 16 * 520; i += 256) h_lds[i] = 0;

  short8 bfrag[2][16];
#pragma unroll
  for (int ni = 0; ni < 2; ++ni) {
    const unsigned short* wb =
        whh + ((size_t)grp * 2048 + (size_t)(w * 512 + j0 + ni * 16 + lo)) * 512 + quad * 8;
#pragma unroll
    for (int kk = 0; kk < 16; ++kk) bfrag[ni][kk] = *(const short8*)(wb + kk * 32);
  }

  const int pb = tid >> 5, pjj = tid & 31;  // pointwise cell (b, jj)
  float creg = 0.0f;

  float ihv[2][4];
  {
    int t0 = d ? 127 : 0;
#pragma unroll
    for (int ni = 0; ni < 2; ++ni) {
      const float* ihp =
          ih + ((size_t)grp * 1024 + (size_t)t0 * 8) * 2048 + (w * 512 + j0 + ni * 16 + lo);
#pragma unroll
      for (int r = 0; r < 4; ++r) {
        int b = quad * 4 + r;
        ihv[ni][r] = (b < 8) ? ihp[(size_t)b * 2048] : 0.0f;
      }
    }
  }

  const int srow = tid >> 5;
  const int scol = (tid & 31) * 16;

  for (int s = 0; s < 128; ++s) {
    const int t = d ? (127 - s) : s;

    // R11: issue ih prefetch for s+1 FIRST; hides under the poll wait.
    float ihvN[2][4];
    if (s < 127) {
      int tn = d ? (126 - s) : (s + 1);
#pragma unroll
      for (int ni = 0; ni < 2; ++ni) {
        const float* ihp =
            ih + ((size_t)grp * 1024 + (size_t)tn * 8) * 2048 + (w * 512 + j0 + ni * 16 + lo);
#pragma unroll
        for (int r = 0; r < 4; ++r) {
          int b = quad * 4 + r;
          ihvN[ni][r] = (b < 8) ? ihp[(size_t)b * 2048] : 0.0f;
        }
      }
    } else {
#pragma unroll
      for (int ni = 0; ni < 2; ++ni)
#pragma unroll
        for (int r = 0; r < 4; ++r) ihvN[ni][r] = 0.0f;
    }

    if (s) {
      const ull* src = stateS + ((size_t)grp * 128 + s) * 1024 + tid * 4;
      ull v0, v1, v2, v3;
      do {
        v0 = __hip_atomic_load(src + 0, __ATOMIC_RELAXED, __HIP_MEMORY_SCOPE_AGENT);
        v1 = __hip_atomic_load(src + 1, __ATOMIC_RELAXED, __HIP_MEMORY_SCOPE_AGENT);
        v2 = __hip_atomic_load(src + 2, __ATOMIC_RELAXED, __HIP_MEMORY_SCOPE_AGENT);
        v3 = __hip_atomic_load(src + 3, __ATOMIC_RELAXED, __HIP_MEMORY_SCOPE_AGENT);
      } while (v0 == POISON || v1 == POISON || v2 == POISON || v3 == POISON);
      unsigned short* dl = h_lds + srow * 520 + scol;
      *(ull*)(dl + 0) = v0;
      *(ull*)(dl + 4) = v1;
      *(ull*)(dl + 8) = v2;
      *(ull*)(dl + 12) = v3;
    }
    LDS_BARRIER();

    floatx4 acc[2] = {};
    floatx4 acc2[2] = {};
    {
      const unsigned short* ar = h_lds + lo * 520 + quad * 8;
#pragma unroll
      for (int kk = 0; kk < 16; kk += 2) {
        short8 a0 = *(const short8*)(ar + kk * 32);
        short8 a1 = *(const short8*)(ar + (kk + 1) * 32);
#pragma unroll
        for (int ni = 0; ni < 2; ++ni) {
          acc[ni]  = __builtin_amdgcn_mfma_f32_16x16x32_bf16(a0, bfrag[ni][kk], acc[ni], 0, 0, 0);
          acc2[ni] = __builtin_amdgcn_mfma_f32_16x16x32_bf16(a1, bfrag[ni][kk + 1], acc2[ni], 0, 0, 0);
        }
      }
    }
#pragma unroll
    for (int ni = 0; ni < 2; ++ni)
#pragma unroll
      for (int r = 0; r < 4; ++r) {
        int b = quad * 4 + r;
        if (b < 8) gbuf[w][b][ni * 16 + lo] = acc[ni][r] + acc2[ni][r] + ihv[ni][r];
      }
    LDS_BARRIER();

    {
      float ig = gbuf[0][pb][pjj], fg = gbuf[1][pb][pjj];
      float gg = gbuf[2][pb][pjj], og = gbuf[3][pb][pjj];
      float cn = sigm(fg) * creg + sigm(ig) * tanh_f(gg);
      creg = cn;
      float h = sigm(og) * tanh_f(cn);

      if (s < 127) {
        unsigned hs = f2bf(h);
        int base = L & ~3;
        unsigned v0 = __shfl(hs, base + 0);
        unsigned v1 = __shfl(hs, base + 1);
        unsigned v2 = __shfl(hs, base + 2);
        unsigned v3 = __shfl(hs, base + 3);
        if ((L & 3) == 0) {
          ull wv = (ull)v0 | ((ull)v1 << 16) | ((ull)v2 << 32) | ((ull)v3 << 48);
          ull* dst = stateS + ((size_t)grp * 128 + (s + 1)) * 1024 + pb * 128 + ((j0 + pjj) >> 2);
          __hip_atomic_store(dst, wv, __ATOMIC_RELAXED, __HIP_MEMORY_SCOPE_AGENT);
        }
      }
      out[(((size_t)pb * 128 + t) * 1024 + d * 512 + j0 + pjj) * 4 + kh] = h;
    }

#pragma unroll
    for (int ni = 0; ni < 2; ++ni)
#pragma unroll
      for (int r = 0; r < 4; ++r) ihv[ni][r] = ihvN[ni][r];
  }
}

extern "C" void kernel_launch(void* const* d_in, const int* in_sizes, int n_in,
                              void* d_out, int out_size, void* d_ws, size_t ws_size,
                              hipStream_t stream) {
  (void)in_sizes; (void)n_in; (void)out_size; (void)ws_size;
  const float* x     = (const float*)d_in[0];
  const float* Wih_f = (const float*)d_in[1];
  const float* Whh_f = (const float*)d_in[2];
  const float* bih_f = (const float*)d_in[3];
  const float* bhh_f = (const float*)d_in[4];
  const float* Wih_b = (const float*)d_in[5];
  const float* Whh_b = (const float*)d_in[6];
  const float* bih_b = (const float*)d_in[7];
  const float* bhh_b = (const float*)d_in[8];
  float* out = (float*)d_out;
  char* ws = (char*)d_ws;

  ull* stateS          = (ull*)ws;                               // 8 MB
  float* ihg           = (float*)(ws + (8ull << 20));            // 64 MB
  unsigned short* Xp   = (unsigned short*)(ws + (72ull << 20));  // 8 MB
  unsigned short* Wihb = (unsigned short*)(ws + (80ull << 20));  // 32 MB
  unsigned short* Whhb = (unsigned short*)(ws + (112ull << 20)); // 16 MB

  prep_k<<<29696, 256, 0, stream>>>(x, Wih_f, Wih_b, Whh_f, Whh_b, Xp, Wihb, Whhb, stateS);
  gemm256_k<<<256, 512, 0, stream>>>(Xp, Wihb, bih_f, bhh_f, bih_b, bhh_b, ihg);
  lstm_rec_k<<<128, 256, 0, stream>>>(ihg, Whhb, out, stateS);
}